// Round 6
// baseline (149.892 us; speedup 1.0000x reference)
//
#include <hip/hip_runtime.h>

// Photoreceptor Rieke model: 40,000 independent nonlinear ODE chains,
// sequential over T=1000, coalesced over p.
// R6: 2 chains per thread (ILP=2). 625 waves on 1024 SIMDs = 0 TLP; R3/R5
// proved neither reg-depth nor fat vmem ops move 72us -> the binder is
// exposed per-instruction latency in a single wave. Interleaving 2
// independent chains fills dep stalls. 20032 threads = 313 blocks x 64,
// every CU covered, <=2 co-resident blocks/CU.
// Also: g^3 carried across steps (out is next step's g3), 1+y4 via fma,
// plain (non-NT) stores so stores ack at L2 and don't clog vmcnt queue.
#define B_ 16
#define T_ 1000
#define P_ 2500
#define HALF 20000                  // chains handled as (b,p) and (b+8,p)

__device__ __forceinline__ float rcp_fast(float v) {
    return __builtin_amdgcn_rcpf(v);   // ~1 ulp, single v_rcp_f32
}

extern "C" __global__ void __launch_bounds__(64, 1)
prk_kernel(const float* __restrict__ x,
           const float* __restrict__ sigma_p,  const float* __restrict__ phi_p,
           const float* __restrict__ eta_p,    const float* __restrict__ c2c_p,
           const float* __restrict__ hill_p,   const float* __restrict__ cdark_p,
           const float* __restrict__ beta_p,   const float* __restrict__ bslow_p,
           const float* __restrict__ hcoef_p,  const float* __restrict__ haff_p,
           const float* __restrict__ gamma_p,  const float* __restrict__ gdark_p,
           float* __restrict__ out)
{
    const int tid = blockIdx.x * 64 + threadIdx.x;
    if (tid >= HALF) return;                      // last 32 lanes of block 312
    const int b0 = tid / P_;                      // 0..7
    const int p0 = tid - b0 * P_;

    const size_t strideB = (size_t)8 * T_ * P_;   // chain B = (b0+8, p0)
    const float* __restrict__ xA = x   + (size_t)b0 * T_ * P_ + p0;
    const float* __restrict__ xB = xA  + strideB;
    float*       __restrict__ oA = out + (size_t)b0 * T_ * P_ + p0;
    float*       __restrict__ oB = oA  + strideB;

    const float sigma        = sigma_p[0];
    const float phi          = phi_p[0];
    const float eta          = eta_p[0];
    const float cgmp2cur     = c2c_p[0];
    const float cgmphill     = hill_p[0];
    const float cdark        = cdark_p[0];
    const float beta         = beta_p[0];
    const float betaSlow     = bslow_p[0];
    const float hillcoef     = hcoef_p[0];
    const float hillaffinity = haff_p[0];
    const float gamma        = gamma_p[0] * 0.125f;  // gamma / timeBin(8)
    const float gdark        = gdark_p[0];
    const float DT = 0.008f;                          // 0.001 * 8

    // derived constants (uniform -> SGPRs)
    const float darkCurrent = powf(gdark, cgmphill) * cgmp2cur * 0.5f;
    const float gdark_ = powf(2.0f * darkCurrent / cgmp2cur, 1.0f / cgmphill);
    const float cur2ca = beta * cdark / darkCurrent;
    const float smax   = eta / phi * gdark_ *
                         (1.0f + powf(cdark / hillaffinity, hillcoef));

    const float Ar  = 1.0f - DT * sigma;
    const float Ap  = 1.0f - DT * phi;
    const float Pe  = DT * eta;
    const float Ac  = 1.0f - DT * beta;
    const float Kc  = DT * cur2ca * cgmp2cur;
    const float Acs = 1.0f - DT * betaSlow;
    const float Bcs = DT * betaSlow;
    const float inv_cd = 1.0f / cdark;
    const float inv_ha = 1.0f / hillaffinity;
    const float outk   = -0.5f * cgmp2cur;

    // per-chain state (g3 = g^3 carried: out[t+1] = outk*g1^3 = next g3)
    struct St { float r, pv, c, cs, s, g, g3; };
    auto initSt = [&](const float* xp) {
        St S;
        S.r  = xp[0] * gamma / sigma;
        S.pv = (eta + S.r) / phi;
        S.g  = gdark_;
        S.g3 = gdark_ * gdark_ * gdark_;
        S.s  = gdark_ * eta / phi;
        S.c  = cdark;
        S.cs = cdark;
        return S;
    };
    St SA = initSt(xA), SB = initSt(xB);
    oA[0] = 0.0f; oB[0] = 0.0f;

    if (cgmphill == 3.0f && hillcoef == 4.0f) {
        // 21-op specialized step; returns output value for row t+1
        auto step = [&](St& S, float xt) -> float {
            float r1  = fmaf(Ar, S.r, gamma * xt);
            float p1  = fmaf(Ap, S.pv, fmaf(DT, S.r, Pe));
            float den = fmaf(S.cs, inv_cd, 1.0f);
            float c1  = fmaf(Ac, S.c, Kc * S.g3 * rcp_fast(den));
            float cs1 = fmaf(Acs, S.cs, Bcs * S.c);
            float yy  = c1 * inv_ha;
            float y2  = yy * yy;
            float s1  = smax * rcp_fast(fmaf(y2, y2, 1.0f));
            float g1  = fmaf(DT, fmaf(-S.pv, S.g, S.s), S.g);
            float g1c = (g1 * g1) * g1;
            S.r = r1; S.pv = p1; S.c = c1; S.cs = cs1; S.s = s1;
            S.g = g1; S.g3 = g1c;
            return outk * g1c;
        };

        constexpr int U = 8;        // 125 chunks: 124 full + 7-step tail
        float A0[U], B0v[U], A1[U], B1v[U], A2[U], B2v[U];

#define SB_ __builtin_amdgcn_sched_barrier(0)
#define LOADC(BA, BB, ck) do {                                           \
            _Pragma("unroll")                                            \
            for (int u = 0; u < U; ++u) {                                \
                const size_t t = (size_t)(8 * (ck) + u);                 \
                BA[u] = xA[t * P_];  BB[u] = xB[t * P_];                 \
            }                                                            \
        } while (0)
#define LOADCL(BA, BB, ck) do {                                          \
            _Pragma("unroll")                                            \
            for (int u = 0; u < U; ++u) {                                \
                int t = 8 * (ck) + u;  t = t > 998 ? 998 : t;            \
                BA[u] = xA[(size_t)t * P_];  BB[u] = xB[(size_t)t * P_]; \
            }                                                            \
        } while (0)
#define COMPC(BA, BB, ck, nst) do {                                      \
            _Pragma("unroll")                                            \
            for (int u = 0; u < (nst); ++u) {                            \
                const size_t t1 = (size_t)(8 * (ck) + u + 1);            \
                float vA = step(SA, BA[u]);                              \
                float vB = step(SB, BB[u]);                              \
                oA[t1 * P_] = vA;  oB[t1 * P_] = vB;                     \
            }                                                            \
        } while (0)

        // prologue: chunks 0,1 in flight
        LOADC(A0, B0v, 0); SB_;
        LOADC(A1, B1v, 1); SB_;

        // main: 40 iters x 3 chunks = chunks 0..119 computed, loads to 121
        #pragma unroll 1
        for (int ci = 0; ci < 120; ci += 3) {
            LOADC(A2, B2v, ci + 2); SB_;  COMPC(A0, B0v, ci, U);     SB_;
            LOADC(A0, B0v, ci + 3); SB_;  COMPC(A1, B1v, ci + 1, U); SB_;
            LOADC(A1, B1v, ci + 4); SB_;  COMPC(A2, B2v, ci + 2, U); SB_;
        }
        // epilogue: chunks 120..124 (124 clamped, 7 live steps t=992..998)
        LOADC (A2, B2v, 122); SB_;  COMPC(A0, B0v, 120, U); SB_;
        LOADC (A0, B0v, 123); SB_;  COMPC(A1, B1v, 121, U); SB_;
        LOADCL(A1, B1v, 124); SB_;  COMPC(A2, B2v, 122, U); SB_;
        COMPC(A0, B0v, 123, U);
        COMPC(A1, B1v, 124, 7);

#undef SB_
#undef LOADC
#undef LOADCL
#undef COMPC
    } else {
        // ---- generic fallback (exact powf; never taken for bench params) ----
        const float* xs[2] = { xA, xB };
        float*       os[2] = { oA, oB };
        St*          ss[2] = { &SA, &SB };
        for (int k = 0; k < 2; ++k) {
            St S = *ss[k];
            for (int t = 0; t < T_ - 1; ++t) {
                float xt  = xs[k][(size_t)t * P_];
                float r1  = S.r + DT * (-sigma * S.r) + gamma * xt;
                float p1  = S.pv + DT * (S.r + eta - phi * S.pv);
                float c1  = S.c + DT * (cur2ca * cgmp2cur * powf(S.g, cgmphill) /
                                        (1.0f + S.cs / cdark) - beta * S.c);
                float cs1 = S.cs - DT * (betaSlow * (S.cs - S.c));
                float s1  = smax / (1.0f + powf(c1 / hillaffinity, hillcoef));
                float g1  = S.g + DT * (S.s - S.pv * S.g);
                os[k][(size_t)(t + 1) * P_] =
                    -(cgmp2cur * powf(g1, cgmphill)) * 0.5f;
                S.r = r1; S.pv = p1; S.c = c1; S.cs = cs1; S.s = s1; S.g = g1;
            }
        }
    }
}

extern "C" void kernel_launch(void* const* d_in, const int* in_sizes, int n_in,
                              void* d_out, int out_size, void* d_ws, size_t ws_size,
                              hipStream_t stream) {
    const float* x = (const float*)d_in[0];
    prk_kernel<<<dim3((HALF + 63) / 64), dim3(64), 0, stream>>>(
        x,
        (const float*)d_in[1],  (const float*)d_in[2],  (const float*)d_in[3],
        (const float*)d_in[4],  (const float*)d_in[5],  (const float*)d_in[6],
        (const float*)d_in[7],  (const float*)d_in[8],  (const float*)d_in[9],
        (const float*)d_in[10], (const float*)d_in[11], (const float*)d_in[12],
        (float*)d_out);
}

// Round 7
// 73.016 us; speedup vs baseline: 2.0529x; 2.0529x over previous
//
#include <hip/hip_runtime.h>

// Photoreceptor Rieke model: 40,000 independent nonlinear ODE chains,
// sequential over T=1000, coalesced over p. 1 thread = 1 chain.
// R7: x staged via __builtin_amdgcn_global_load_lds (async DMA, no VGPRs ->
// compiler cannot collapse the pipeline; R1-R6 VGPR counts proved every
// register pipeline was defeated). Triple-buffered LDS chunks, hand-counted
// s_waitcnt vmcnt(N) (never 0 in steady state). 1 wave/block: no barriers.
#define B_ 16
#define T_ 1000
#define P_ 2500
#define NCH (B_ * P_)   // 40000 = 625 blocks * 64 threads exactly

#define AS1 __attribute__((address_space(1)))
#define AS3 __attribute__((address_space(3)))

__device__ __forceinline__ float rcp_fast(float v) {
    return __builtin_amdgcn_rcpf(v);   // ~1 ulp, single v_rcp_f32
}

extern "C" __global__ void __launch_bounds__(64, 1)
prk_kernel(const float* __restrict__ x,
           const float* __restrict__ sigma_p,  const float* __restrict__ phi_p,
           const float* __restrict__ eta_p,    const float* __restrict__ c2c_p,
           const float* __restrict__ hill_p,   const float* __restrict__ cdark_p,
           const float* __restrict__ beta_p,   const float* __restrict__ bslow_p,
           const float* __restrict__ hcoef_p,  const float* __restrict__ haff_p,
           const float* __restrict__ gamma_p,  const float* __restrict__ gdark_p,
           float* __restrict__ out)
{
    const int lane = threadIdx.x;
    const int cid  = blockIdx.x * 64 + lane;
    const int b    = cid / P_;
    const int p    = cid - b * P_;

    const float sigma        = sigma_p[0];
    const float phi          = phi_p[0];
    const float eta          = eta_p[0];
    const float cgmp2cur     = c2c_p[0];
    const float cgmphill     = hill_p[0];
    const float cdark        = cdark_p[0];
    const float beta         = beta_p[0];
    const float betaSlow     = bslow_p[0];
    const float hillcoef     = hcoef_p[0];
    const float hillaffinity = haff_p[0];
    const float gamma        = gamma_p[0] * 0.125f;  // gamma / timeBin(8)
    const float gdark        = gdark_p[0];
    const float DT = 0.008f;                          // 0.001 * 8

    // derived constants (uniform -> SGPRs)
    const float darkCurrent = powf(gdark, cgmphill) * cgmp2cur * 0.5f;
    const float gdark_ = powf(2.0f * darkCurrent / cgmp2cur, 1.0f / cgmphill);
    const float cur2ca = beta * cdark / darkCurrent;
    const float smax   = eta / phi * gdark_ *
                         (1.0f + powf(cdark / hillaffinity, hillcoef));

    const float Ar  = 1.0f - DT * sigma;
    const float Ap  = 1.0f - DT * phi;
    const float Pe  = DT * eta;
    const float Ac  = 1.0f - DT * beta;
    const float Kc  = DT * cur2ca * cgmp2cur;
    const float Acs = 1.0f - DT * betaSlow;
    const float Bcs = DT * betaSlow;
    const float inv_cd = 1.0f / cdark;
    const float inv_ha = 1.0f / hillaffinity;
    const float outk   = -0.5f * cgmp2cur;

    const float* __restrict__ xrow = x   + (size_t)b * T_ * P_ + p;  // per-lane
    float*       __restrict__ op   = out + (size_t)b * T_ * P_ + p;

    // initial state; g3 = g^3 carried across steps (out = outk * g3_next)
    float r  = xrow[0] * gamma / sigma;
    float pv = (eta + r) / phi;
    float g  = gdark_;
    float g3 = gdark_ * gdark_ * gdark_;
    float s  = gdark_ * eta / phi;
    float c  = cdark;
    float cs = cdark;
    op[0] = 0.0f;                       // out row 0 = 0

    if (cgmphill == 3.0f && hillcoef == 4.0f) {
        // 3 buffers x 16 rows x 64 lanes = 12 KB LDS
        __shared__ float xlds[3][16][64];

#define WAITV(n) do {                                                    \
            asm volatile("s_waitcnt vmcnt(" #n ")" ::: "memory");        \
            __builtin_amdgcn_sched_barrier(0);                           \
        } while (0)
// stage chunk ck (rows 16ck..16ck+15, clamped at 998) into buffer ck%3
#define STAGE(ck) do {                                                   \
            const int _bi = (ck) % 3;                                    \
            _Pragma("unroll")                                            \
            for (int _u = 0; _u < 16; ++_u) {                            \
                int _tt = 16 * (ck) + _u;                                \
                _tt = _tt > 998 ? 998 : _tt;                             \
                __builtin_amdgcn_global_load_lds(                        \
                    (const AS1 void*)(const void*)(xrow + (size_t)_tt * P_), \
                    (AS3 void*)(void*)&xlds[_bi][_u][0], 4, 0, 0);       \
            }                                                            \
        } while (0)
// compute nst steps of chunk ck from buffer ck%3 (writes out rows 16ck+1..)
#define COMP(ck, nst) do {                                               \
            const int _bi = (ck) % 3;                                    \
            _Pragma("unroll")                                            \
            for (int _u = 0; _u < (nst); ++_u) {                         \
                float xt  = xlds[_bi][_u][lane];                         \
                float r1  = fmaf(Ar, r, gamma * xt);                     \
                float p1  = fmaf(Ap, pv, fmaf(DT, r, Pe));               \
                float den = fmaf(cs, inv_cd, 1.0f);                      \
                float c1  = fmaf(Ac, c, Kc * g3 * rcp_fast(den));        \
                float cs1 = fmaf(Acs, cs, Bcs * c);                      \
                float yy  = c1 * inv_ha;                                 \
                float y2  = yy * yy;                                     \
                float s1  = smax * rcp_fast(fmaf(y2, y2, 1.0f));         \
                float g1  = fmaf(DT, fmaf(-pv, g, s), g);                \
                float g1c = (g1 * g1) * g1;                              \
                __builtin_nontemporal_store(outk * g1c,                  \
                    op + (size_t)(16 * (ck) + _u + 1) * P_);             \
                r = r1; pv = p1; c = c1; cs = cs1; s = s1;               \
                g = g1; g3 = g1c;                                        \
            }                                                            \
        } while (0)

        // prologue: chunks 0,1 in flight (32 loads outstanding)
        STAGE(0); STAGE(1);
        // phase 0: younger-than-L0 = L1 (16) -> vmcnt(16) proves L0 landed
        WAITV(16); COMP(0, 16); STAGE(2);
        // phases 1..60: younger-than-L(k) = S(k-1) 16 + L(k+1) 16 = 32
        #pragma unroll 1
        for (int kk = 1; kk <= 58; kk += 3) {
            WAITV(32); COMP(kk,     16); STAGE(kk + 2);
            WAITV(32); COMP(kk + 1, 16); STAGE(kk + 3);
            WAITV(32); COMP(kk + 2, 16); STAGE(kk + 4);
        }
        // phase 61: younger-than-L61 = S60 + L62 = 32
        WAITV(32); COMP(61, 16);
        // phase 62: younger-than-L62 = S61 (16); 7 live steps t=992..998
        WAITV(16); COMP(62, 7);

#undef WAITV
#undef STAGE
#undef COMP
    } else {
        // ---- generic fallback (exact powf; never taken for bench params) ----
        for (int t = 0; t < T_ - 1; ++t) {
            float xt  = xrow[(size_t)t * P_];
            float r1  = r + DT * (-sigma * r) + gamma * xt;
            float p1  = pv + DT * (r + eta - phi * pv);
            float c1  = c + DT * (cur2ca * cgmp2cur * powf(g, cgmphill) /
                                  (1.0f + cs / cdark) - beta * c);
            float cs1 = cs - DT * (betaSlow * (cs - c));
            float s1  = smax / (1.0f + powf(c1 / hillaffinity, hillcoef));
            float g1  = g + DT * (s - pv * g);
            op[(size_t)(t + 1) * P_] = -(cgmp2cur * powf(g1, cgmphill)) * 0.5f;
            r = r1; pv = p1; c = c1; cs = cs1; s = s1; g = g1;
        }
    }
}

extern "C" void kernel_launch(void* const* d_in, const int* in_sizes, int n_in,
                              void* d_out, int out_size, void* d_ws, size_t ws_size,
                              hipStream_t stream) {
    const float* x = (const float*)d_in[0];
    prk_kernel<<<dim3(NCH / 64), dim3(64), 0, stream>>>(
        x,
        (const float*)d_in[1],  (const float*)d_in[2],  (const float*)d_in[3],
        (const float*)d_in[4],  (const float*)d_in[5],  (const float*)d_in[6],
        (const float*)d_in[7],  (const float*)d_in[8],  (const float*)d_in[9],
        (const float*)d_in[10], (const float*)d_in[11], (const float*)d_in[12],
        (float*)d_out);
}